// Round 1
// baseline (82.656 us; speedup 1.0000x reference)
//
#include <hip/hip_runtime.h>
#include <hip/hip_bf16.h>

// Problem constants (from reference setup_inputs):
// B=2, K=64, N=16, C=2N=32, Hf=Wf=128, H=W=128
#define B_ 2
#define K_ 64
#define N_ 16
#define C_ 32
#define HF_ 128
#define WF_ 128
#define H_ 128
#define W_ 128
#define HW_ (H_ * W_)              // 16384
#define TILES_PER_BK (HW_ / 256)   // 64
#define NBLOCKS (B_ * K_ * TILES_PER_BK)  // 8192
#define TOTAL_ELEMS ((double)(B_ * K_ * H_ * W_))  // 2097152

__global__ __launch_bounds__(256) void gauss_bce_partial(
    const float* __restrict__ centers,  // (B, 32, 128*128)
    const float* __restrict__ radius,   // (B, 1, 128*128)
    const float* __restrict__ mask,     // (B, K)
    const int*   __restrict__ ind,      // (B, K)
    const float* __restrict__ target,   // (B, K, H, W)
    const float* __restrict__ peak,     // (B, K, 2)
    float* __restrict__ partials)       // (NBLOCKS)
{
    __shared__ float sx[N_];
    __shared__ float sy[N_];
    __shared__ float s_inv2r2;
    __shared__ float s_m;
    __shared__ float warp_sums[4];

    const int tid  = threadIdx.x;
    const int bk   = blockIdx.x >> 6;       // / TILES_PER_BK
    const int tile = blockIdx.x & 63;
    const int b = bk >> 6;                  // / K_
    const int k = bk & 63;

    // Stage per-(b,k) constants into LDS.
    if (tid < C_) {
        const int ii = ind[b * K_ + k];     // flat index into Hf*Wf
        const float v = centers[(size_t)(b * C_ + tid) * (HF_ * WF_) + ii];
        const int n = tid >> 1;
        if ((tid & 1) == 0) {
            sx[n] = v + peak[(b * K_ + k) * 2 + 0];
        } else {
            sy[n] = v + peak[(b * K_ + k) * 2 + 1];
        }
    } else if (tid == C_) {
        const int ii = ind[b * K_ + k];
        const float r = radius[(size_t)b * (HF_ * WF_) + ii];
        s_inv2r2 = 1.0f / (2.0f * r * r);
    } else if (tid == C_ + 1) {
        s_m = mask[b * K_ + k];
    }
    __syncthreads();

    const int pix = tile * 256 + tid;
    const int h = pix >> 7;      // / W_
    const int w = pix & 127;
    const float fx = (float)w;
    const float fy = (float)h;
    const float inv2r2 = s_inv2r2;
    const float m = s_m;

    float g = 0.0f;
    #pragma unroll
    for (int n = 0; n < N_; ++n) {
        const float dx = sx[n] - fx;
        const float dy = sy[n] - fy;
        g += __expf(-(dx * dx + dy * dy) * inv2r2);
    }

    const float sig = 1.0f / (1.0f + __expf(-g));
    float p = sig * m;
    const float t = target[((size_t)(b * K_ + k) * H_ + h) * W_ + w] * m;

    float pc  = fminf(fmaxf(p, 1e-12f), 1.0f);
    float omp = fminf(fmaxf(1.0f - p, 1e-12f), 1.0f);
    float bce = -(t * __logf(pc) + (1.0f - t) * __logf(omp));

    // Block reduction: wave64 shuffle, then LDS across the 4 waves.
    float v = bce;
    #pragma unroll
    for (int off = 32; off > 0; off >>= 1)
        v += __shfl_down(v, off, 64);
    const int lane = tid & 63;
    const int wid  = tid >> 6;
    if (lane == 0) warp_sums[wid] = v;
    __syncthreads();
    if (tid == 0) {
        partials[blockIdx.x] = warp_sums[0] + warp_sums[1] + warp_sums[2] + warp_sums[3];
    }
}

__global__ __launch_bounds__(256) void reduce_final(
    const float* __restrict__ partials, float* __restrict__ out)
{
    __shared__ double warp_sums[4];
    const int tid = threadIdx.x;
    double acc = 0.0;
    #pragma unroll
    for (int i = 0; i < NBLOCKS / 256; ++i)
        acc += (double)partials[i * 256 + tid];

    #pragma unroll
    for (int off = 32; off > 0; off >>= 1)
        acc += __shfl_down(acc, off, 64);
    const int lane = tid & 63;
    const int wid  = tid >> 6;
    if (lane == 0) warp_sums[wid] = acc;
    __syncthreads();
    if (tid == 0) {
        double s = warp_sums[0] + warp_sums[1] + warp_sums[2] + warp_sums[3];
        float loss = (float)(s / TOTAL_ELEMS);
        out[0] = loss;
        out[1] = loss;
    }
}

extern "C" void kernel_launch(void* const* d_in, const int* in_sizes, int n_in,
                              void* d_out, int out_size, void* d_ws, size_t ws_size,
                              hipStream_t stream) {
    const float* centers = (const float*)d_in[0];
    const float* radius  = (const float*)d_in[1];
    const float* mask    = (const float*)d_in[2];
    const int*   ind     = (const int*)d_in[3];
    const float* target  = (const float*)d_in[4];
    const float* peak    = (const float*)d_in[5];
    float* out = (float*)d_out;
    float* partials = (float*)d_ws;   // NBLOCKS floats = 32 KB, well within ws

    gauss_bce_partial<<<NBLOCKS, 256, 0, stream>>>(
        centers, radius, mask, ind, target, peak, partials);
    reduce_final<<<1, 256, 0, stream>>>(partials, out);
}

// Round 2
// 82.616 us; speedup vs baseline: 1.0005x; 1.0005x over previous
//
#include <hip/hip_runtime.h>
#include <hip/hip_bf16.h>

// Problem constants (from reference setup_inputs):
// B=2, K=64, N=16, C=2N=32, Hf=Wf=128, H=W=128
#define B_ 2
#define K_ 64
#define N_ 16
#define C_ 32
#define HF_ 128
#define WF_ 128
#define H_ 128
#define W_ 128
#define HW_ (H_ * W_)                 // 16384
#define PIX_PER_THREAD 4
#define PIX_PER_BLOCK (256 * PIX_PER_THREAD)       // 1024
#define TILES_PER_BK (HW_ / PIX_PER_BLOCK)         // 16
#define NBLOCKS (B_ * K_ * TILES_PER_BK)           // 2048
#define TOTAL_ELEMS ((double)(B_ * K_ * H_ * W_))  // 2097152
#define LOG2E 1.44269504088896f

__global__ __launch_bounds__(256) void gauss_bce_partial(
    const float* __restrict__ centers,  // (B, 32, 128*128)
    const float* __restrict__ radius,   // (B, 1, 128*128)
    const float* __restrict__ mask,     // (B, K)
    const int*   __restrict__ ind,      // (B, K)
    const float* __restrict__ target,   // (B, K, H, W)
    const float* __restrict__ peak,     // (B, K, 2)
    float* __restrict__ partials)       // (NBLOCKS)
{
    __shared__ float sx[N_];
    __shared__ float sy[N_];
    __shared__ float s_c2;     // -log2(e) / (2 r^2)
    __shared__ float s_m;
    __shared__ float warp_sums[4];

    const int tid  = threadIdx.x;
    const int bk   = blockIdx.x >> 4;       // / TILES_PER_BK
    const int tile = blockIdx.x & (TILES_PER_BK - 1);
    const int b = bk >> 6;                  // / K_
    const int k = bk & 63;

    // Stage per-(b,k) constants into LDS.
    if (tid < C_) {
        const int ii = ind[b * K_ + k];     // flat index into Hf*Wf
        const float v = centers[(size_t)(b * C_ + tid) * (HF_ * WF_) + ii];
        const int n = tid >> 1;
        if ((tid & 1) == 0) {
            sx[n] = v + peak[(b * K_ + k) * 2 + 0];
        } else {
            sy[n] = v + peak[(b * K_ + k) * 2 + 1];
        }
    } else if (tid == C_) {
        const int ii = ind[b * K_ + k];
        const float r = radius[(size_t)b * (HF_ * WF_) + ii];
        s_c2 = -LOG2E / (2.0f * r * r);
    } else if (tid == C_ + 1) {
        s_m = mask[b * K_ + k];
    }
    __syncthreads();

    const int pix0 = tile * PIX_PER_BLOCK + tid * PIX_PER_THREAD;
    const int h  = pix0 >> 7;      // / W_
    const int w0 = pix0 & 127;     // multiple of 4
    const float fy = (float)h;
    const float c2 = s_c2;
    const float m  = s_m;

    // Vectorized target load (coalesced, 16 B/lane).
    const float4 t4 = *(const float4*)&target[((size_t)(b * K_ + k) * H_ + h) * W_ + w0];
    const float tvals[4] = {t4.x, t4.y, t4.z, t4.w};

    // Hoist y-distances (shared by the 4 x-neighbors) and x-centers to regs.
    float dy2[N_], sxr[N_];
    #pragma unroll
    for (int n = 0; n < N_; ++n) {
        const float dy = sy[n] - fy;
        dy2[n] = dy * dy;
        sxr[n] = sx[n];
    }

    float acc = 0.0f;
    #pragma unroll
    for (int j = 0; j < PIX_PER_THREAD; ++j) {
        const float fx = (float)(w0 + j);
        float g = 0.0f;
        #pragma unroll
        for (int n = 0; n < N_; ++n) {
            const float dx = sxr[n] - fx;
            g += exp2f(__builtin_fmaf(dx, dx, dy2[n]) * c2);
        }
        const float e   = __expf(-g);
        const float sig = __builtin_amdgcn_rcpf(1.0f + e);
        const float p = sig * m;
        const float t = tvals[j] * m;
        const float pc  = fminf(fmaxf(p, 1e-12f), 1.0f);
        const float omp = fminf(fmaxf(1.0f - p, 1e-12f), 1.0f);
        acc += -(t * __logf(pc) + (1.0f - t) * __logf(omp));
    }

    // Block reduction: wave64 shuffle, then LDS across the 4 waves.
    float v = acc;
    #pragma unroll
    for (int off = 32; off > 0; off >>= 1)
        v += __shfl_down(v, off, 64);
    const int lane = tid & 63;
    const int wid  = tid >> 6;
    if (lane == 0) warp_sums[wid] = v;
    __syncthreads();
    if (tid == 0) {
        partials[blockIdx.x] = warp_sums[0] + warp_sums[1] + warp_sums[2] + warp_sums[3];
    }
}

__global__ __launch_bounds__(256) void reduce_final(
    const float* __restrict__ partials, float* __restrict__ out)
{
    __shared__ double warp_sums[4];
    const int tid = threadIdx.x;
    double acc = 0.0;
    #pragma unroll
    for (int i = 0; i < NBLOCKS / 256; ++i)
        acc += (double)partials[i * 256 + tid];

    #pragma unroll
    for (int off = 32; off > 0; off >>= 1)
        acc += __shfl_down(acc, off, 64);
    const int lane = tid & 63;
    const int wid  = tid >> 6;
    if (lane == 0) warp_sums[wid] = acc;
    __syncthreads();
    if (tid == 0) {
        double s = warp_sums[0] + warp_sums[1] + warp_sums[2] + warp_sums[3];
        float loss = (float)(s / TOTAL_ELEMS);
        out[0] = loss;
        out[1] = loss;
    }
}

extern "C" void kernel_launch(void* const* d_in, const int* in_sizes, int n_in,
                              void* d_out, int out_size, void* d_ws, size_t ws_size,
                              hipStream_t stream) {
    const float* centers = (const float*)d_in[0];
    const float* radius  = (const float*)d_in[1];
    const float* mask    = (const float*)d_in[2];
    const int*   ind     = (const int*)d_in[3];
    const float* target  = (const float*)d_in[4];
    const float* peak    = (const float*)d_in[5];
    float* out = (float*)d_out;
    float* partials = (float*)d_ws;   // NBLOCKS floats = 8 KB

    gauss_bce_partial<<<NBLOCKS, 256, 0, stream>>>(
        centers, radius, mask, ind, target, peak, partials);
    reduce_final<<<1, 256, 0, stream>>>(partials, out);
}